// Round 5
// baseline (5495.668 us; speedup 1.0000x reference)
//
#include <hip/hip_runtime.h>

// GADBase guided anisotropic diffusion on MI355X — round 5.
// R4 -> R5: hipLaunchCooperativeKernel failed at runtime (out never written;
// absmax == stub value). Co-residency is all the flag protocol needs, so use
// a REGULAR launch with grid == guaranteed-occupancy capacity:
// __launch_bounds__(256,2) => 2 blocks/CU resource-guaranteed; 512 blocks on
// 256 idle CUs are all resident (no block can retire early — each spins on
// neighbors). Flag protocol is publish-then-wait, double-buffered; buffer A
// is only overwritten after the consumer's flag proves it consumed A.

#define BB 2
#define HH 1024
#define WW 1024
#define NPIX (HH * WW)
#define CVN (1023 * 1024)
#define CVPN (1025 * 1024)
#define SHW (128 * 128)
#define LL 0.24f
#define KK2 (0.03f * 0.03f)
#define EPSF 1e-8f
#define DEPSF 0.1f
#define NPRE 64
#define NB 512            // persistent grid: 2 per CU on 256 CUs
#define TPB 256
#define FSTRIDE 16        // flags padded to one cacheline each

__global__ void setup_kernel(const float* __restrict__ src, float* __restrict__ shiftOut,
                             unsigned* __restrict__ flags) {
    int tid = threadIdx.x;
    // zero neighbor-sync flags (ws is 0xAA-poisoned before every call)
    for (int i = tid; i < NB * FSTRIDE; i += TPB) flags[i] = 0u;
    float m = 1e30f;
    for (int i = tid; i < BB * SHW; i += TPB) m = fminf(m, src[i]);
    for (int off = 32; off > 0; off >>= 1) m = fminf(m, __shfl_down(m, off));
    __shared__ float sm[4];
    if ((tid & 63) == 0) sm[tid >> 6] = m;
    __syncthreads();
    if (tid == 0) {
        float mm = fminf(fminf(sm[0], sm[1]), fminf(sm[2], sm[3]));
        shiftOut[0] = (mm <= DEPSF) ? DEPSF : 0.0f;
    }
}

__global__ void init_kernel(const float* __restrict__ guide, const float* __restrict__ yb,
                            const float* __restrict__ shiftPtr, float* __restrict__ img0,
                            float* __restrict__ cv_out, float* __restrict__ ch_out,
                            float* __restrict__ cvp, float* __restrict__ chp) {
    int idx = blockIdx.x * blockDim.x + threadIdx.x;
    if (idx >= BB * NPIX) return;
    int b = idx >> 20;
    int p = idx & (NPIX - 1);
    int y = p >> 10;
    int x = p & 1023;
    const float* gb = guide + (size_t)b * 3 * NPIX;
    const float* yBb = yb + (size_t)b * NPIX;
    float c0 = yBb[p];
    img0[(size_t)b * NPIX + p] = c0 + shiftPtr[0];
    // shift cancels in finite diffs -> cv/ch from raw y_bicubic.
    float* cvpb = cvp + (size_t)b * CVPN;
    float* chpb = chp + (size_t)b * NPIX;
    if (y < HH - 1) {
        float d = fabsf(gb[p + WW] - gb[p])
                + fabsf(gb[NPIX + p + WW] - gb[NPIX + p])
                + fabsf(gb[2 * NPIX + p + WW] - gb[2 * NPIX + p])
                + fabsf(yBb[p + WW] - c0);
        d *= 0.25f;
        float v = 1.0f / (1.0f + (d * d) / KK2);
        cv_out[(size_t)b * CVN + y * WW + x] = v;
        cvpb[(y + 1) * WW + x] = v;           // padded: row r holds cv[r-1]
    } else {
        cvpb[x] = 0.f;
        cvpb[1024 * WW + x] = 0.f;
    }
    if (x < WW - 1) {
        float d = fabsf(gb[p + 1] - gb[p])
                + fabsf(gb[NPIX + p + 1] - gb[NPIX + p])
                + fabsf(gb[2 * NPIX + p + 1] - gb[2 * NPIX + p])
                + fabsf(yBb[p + 1] - c0);
        d *= 0.25f;
        float v = 1.0f / (1.0f + (d * d) / KK2);
        ch_out[(size_t)b * CVN + y * 1023 + x] = v;
        chpb[y * WW + x] = v;                 // padded stride-1024, col 1023 = 0
    } else {
        chpb[y * WW + 1023] = 0.f;
    }
}

__device__ inline void spin_ge(const unsigned* f, unsigned target) {
    while (__hip_atomic_load(f, __ATOMIC_RELAXED, __HIP_MEMORY_SCOPE_AGENT) < target)
        __builtin_amdgcn_s_sleep(2);
    __threadfence();   // acquire: order halo-buffer reads after flag observation
}

// LDS tile: row i <-> global row tileY*32-1+i (i=0..33), col j <-> tile col j-1
#define IMT(i, j) imt[(i) * 132 + (j)]

__launch_bounds__(TPB, 2)
__global__ void persist_kernel(const float* __restrict__ img0, float* __restrict__ out,
                               const float* __restrict__ cvp, const float* __restrict__ chp,
                               const float* __restrict__ src, const float* __restrict__ mask,
                               const float* __restrict__ shiftPtr,
                               float* __restrict__ bufRow, float* __restrict__ bufCol,
                               unsigned* __restrict__ flags) {
    __shared__ float imt[34 * 132];
    int blk = blockIdx.x;
    int b = blk >> 8;
    int r = blk & 255;
    int tileY = r >> 3;          // 0..31
    int tileX = r & 7;           // 0..7
    int tid = threadIdx.x;
    int cyL = tid >> 5;          // 0..7
    int g = tid & 31;            // 0..31
    int lx0 = g * 4;
    int ly0 = cyL * 4;
    int gx = tileX * 128 + lx0;
    int gy = tileY * 32 + ly0;   // first global row owned by this thread

    const float* im0 = img0 + (size_t)b * NPIX;
    const float* cvpb = cvp + (size_t)b * CVPN;
    const float* chpb = chp + (size_t)b * NPIX;
    float shift = shiftPtr[0];

    // conductances resident in registers for all 64 steps
    float4 cvR[5], chR[4];
    float hmR[4];
#pragma unroll
    for (int j = 0; j < 5; ++j)
        cvR[j] = *(const float4*)(cvpb + (size_t)(gy + j) * WW + gx);
#pragma unroll
    for (int k = 0; k < 4; ++k) {
        chR[k] = *(const float4*)(chpb + (size_t)(gy + k) * WW + gx);
        hmR[k] = (gx > 0) ? chpb[(size_t)(gy + k) * WW + gx - 1] : 0.f;
    }
    int sy = tileY * 4 + (cyL >> 1);
    int sx = tileX * 16 + (g >> 1);
    int sidx = b * SHW + sy * 128 + sx;
    float sval = src[sidx] + shift;
    bool masked = mask[sidx] < 0.5f;

    // initial LDS fill (interior + halos from init image; 0 past image edges,
    // where the matching conductance is 0 so the value is never used)
#pragma unroll
    for (int k = 0; k < 4; ++k)
        *(float4*)&IMT(1 + ly0 + k, 1 + lx0) = *(const float4*)(im0 + (size_t)(gy + k) * WW + gx);
    float4 z4 = make_float4(0.f, 0.f, 0.f, 0.f);
    if (cyL == 0)
        *(float4*)&IMT(0, 1 + lx0) =
            (tileY > 0) ? *(const float4*)(im0 + (size_t)(gy - 1) * WW + gx) : z4;
    if (cyL == 7)
        *(float4*)&IMT(33, 1 + lx0) =
            (tileY < 31) ? *(const float4*)(im0 + (size_t)(gy + 4) * WW + gx) : z4;
    if (g == 0) {
#pragma unroll
        for (int k = 0; k < 4; ++k)
            IMT(1 + ly0 + k, 0) = (tileX > 0) ? im0[(size_t)(gy + k) * WW + gx - 1] : 0.f;
    }
    if (g == 31) {
#pragma unroll
        for (int k = 0; k < 4; ++k)
            IMT(1 + ly0 + k, 129) = (tileX < 7) ? im0[(size_t)(gy + k) * WW + gx + 4] : 0.f;
    }
    __syncthreads();

    float4 nv[4];
    for (int t = 0; t < NPRE; ++t) {
        if (t > 0) {
            int buf = (t - 1) & 1;
            // each stager spins on the flag guarding the data it stages
            if (cyL == 0 && tileY > 0) {
                spin_ge(&flags[(blk - 8) * FSTRIDE], (unsigned)t);
                *(float4*)&IMT(0, 1 + lx0) =
                    *(const float4*)&bufRow[(((size_t)buf * NB + blk - 8) * 2 + 1) * 128 + lx0];
            }
            if (cyL == 7 && tileY < 31) {
                spin_ge(&flags[(blk + 8) * FSTRIDE], (unsigned)t);
                *(float4*)&IMT(33, 1 + lx0) =
                    *(const float4*)&bufRow[(((size_t)buf * NB + blk + 8) * 2 + 0) * 128 + lx0];
            }
            if (g == 0 && tileX > 0) {
                spin_ge(&flags[(blk - 1) * FSTRIDE], (unsigned)t);
#pragma unroll
                for (int k = 0; k < 4; ++k)
                    IMT(1 + ly0 + k, 0) =
                        bufCol[(((size_t)buf * NB + blk - 1) * 2 + 1) * 32 + ly0 + k];
            }
            if (g == 31 && tileX < 7) {
                spin_ge(&flags[(blk + 1) * FSTRIDE], (unsigned)t);
#pragma unroll
                for (int k = 0; k < 4; ++k)
                    IMT(1 + ly0 + k, 129) =
                        bufCol[(((size_t)buf * NB + blk + 1) * 2 + 0) * 32 + ly0 + k];
            }
            __syncthreads();   // halos staged before anyone computes
        }

        // diffuse + adjust from LDS state_t -> nv = state_{t+1}
        float4 rUp = *(float4*)&IMT(ly0, 1 + lx0);
        float4 rC  = *(float4*)&IMT(ly0 + 1, 1 + lx0);
        float csum = 0.f;
#pragma unroll
        for (int k = 0; k < 4; ++k) {
            float4 rDn = *(float4*)&IMT(ly0 + 2 + k, 1 + lx0);
            float4 cu = cvR[k], cd = cvR[k + 1], h4 = chR[k];
            float xl = __shfl_up(rC.w, 1);
            float xr = __shfl_down(rC.x, 1);
            float hm = hmR[k];
            if (g == 0)  xl = IMT(1 + ly0 + k, 0);
            if (g == 31) xr = IMT(1 + ly0 + k, 129);
            float4 acc;
            acc.x = rC.x + LL * (cd.x * (rDn.x - rC.x) - cu.x * (rC.x - rUp.x)
                               + h4.x * (rC.y - rC.x) - hm   * (rC.x - xl));
            acc.y = rC.y + LL * (cd.y * (rDn.y - rC.y) - cu.y * (rC.y - rUp.y)
                               + h4.y * (rC.z - rC.y) - h4.x * (rC.y - rC.x));
            acc.z = rC.z + LL * (cd.z * (rDn.z - rC.z) - cu.z * (rC.z - rUp.z)
                               + h4.z * (rC.w - rC.z) - h4.y * (rC.z - rC.y));
            acc.w = rC.w + LL * (cd.w * (rDn.w - rC.w) - cu.w * (rC.w - rUp.w)
                               + h4.w * (xr   - rC.w) - h4.z * (rC.w - rC.z));
            nv[k] = acc;
            csum += acc.x + acc.y + acc.z + acc.w;
            rUp = rC; rC = rDn;
        }
        csum += __shfl_xor(csum, 1);
        csum += __shfl_xor(csum, 32);
        float ratio = masked ? 1.0f : sval / (csum * (1.0f / 64.0f) + EPSF);
#pragma unroll
        for (int k = 0; k < 4; ++k) {
            nv[k].x *= ratio; nv[k].y *= ratio; nv[k].z *= ratio; nv[k].w *= ratio;
        }

        if (t < NPRE - 1) {
            __syncthreads();   // all reads of state_t done
#pragma unroll
            for (int k = 0; k < 4; ++k)
                *(float4*)&IMT(1 + ly0 + k, 1 + lx0) = nv[k];
            int buf = t & 1;
            if (cyL == 0)
                *(float4*)&bufRow[(((size_t)buf * NB + blk) * 2 + 0) * 128 + lx0] = nv[0];
            if (cyL == 7)
                *(float4*)&bufRow[(((size_t)buf * NB + blk) * 2 + 1) * 128 + lx0] = nv[3];
            if (g == 0) {
#pragma unroll
                for (int k = 0; k < 4; ++k)
                    bufCol[(((size_t)buf * NB + blk) * 2 + 0) * 32 + ly0 + k] = nv[k].x;
            }
            if (g == 31) {
#pragma unroll
                for (int k = 0; k < 4; ++k)
                    bufCol[(((size_t)buf * NB + blk) * 2 + 1) * 32 + ly0 + k] = nv[k].w;
            }
            __syncthreads();   // LDS writes + edge publishes drained
            if (tid == 0) {
                __threadfence();   // release: edge-buffer stores visible before flag
                __hip_atomic_store(&flags[blk * FSTRIDE], (unsigned)(t + 1),
                                   __ATOMIC_RELAXED, __HIP_MEMORY_SCOPE_AGENT);
            }
        }
    }

    // final output: state_64 - shift, straight from registers
    float* ob = out + (size_t)b * NPIX;
#pragma unroll
    for (int k = 0; k < 4; ++k) {
        float4 v = nv[k];
        v.x -= shift; v.y -= shift; v.z -= shift; v.w -= shift;
        *(float4*)(ob + (size_t)(gy + k) * WW + gx) = v;
    }
}

extern "C" void kernel_launch(void* const* d_in, const int* in_sizes, int n_in,
                              void* d_out, int out_size, void* d_ws, size_t ws_size,
                              hipStream_t stream) {
    const float* guide = (const float*)d_in[0];   // [2,3,1024,1024]
    const float* yb    = (const float*)d_in[1];   // [2,1,1024,1024]
    const float* src   = (const float*)d_in[2];   // [2,1,128,128]
    const float* mask  = (const float*)d_in[3];   // [2,1,128,128]

    float* out    = (float*)d_out;                       // y_pred [2,1,1024,1024]
    float* out_cv = out + (size_t)BB * NPIX;
    float* out_ch = out_cv + (size_t)BB * CVN;

    float* wsf = (float*)d_ws;
    float* shift = wsf;                                  // [256] slot
    unsigned* flags = (unsigned*)(wsf + 256);            // 512*16 uints
    float* imgA = wsf + 256 + NB * FSTRIDE;              // init image, 2*NPIX
    float* cvp  = imgA + (size_t)BB * NPIX;              // 2*1025*1024
    float* chp  = cvp + (size_t)BB * CVPN;               // 2*1024*1024
    float* bufRow = chp + (size_t)BB * NPIX;             // 2*512*2*128
    float* bufCol = bufRow + (size_t)2 * NB * 2 * 128;   // 2*512*2*32

    setup_kernel<<<1, TPB, 0, stream>>>(src, shift, flags);
    init_kernel<<<(BB * NPIX) / TPB, TPB, 0, stream>>>(guide, yb, shift, imgA,
                                                       out_cv, out_ch, cvp, chp);

    persist_kernel<<<NB, TPB, 0, stream>>>(imgA, out, cvp, chp, src, mask, shift,
                                           bufRow, bufCol, flags);
}

// Round 6
// 438.233 us; speedup vs baseline: 12.5405x; 12.5405x over previous
//
#include <hip/hip_runtime.h>

// GADBase guided anisotropic diffusion on MI355X — round 6.
// R5 -> R6: kill the fence storm. R5's __threadfence() (agent acq/rel) emits
// buffer_wbl2/buffer_inv per block per step -> TCC serialization ~84 us/step
// (VALUBusy 0.86%). R6: halo data + flags are SYSTEM-scope RELAXED atomics
// (global_load/store sc0 sc1 -> coherence point is the MALL, no cache
// maintenance). Producer ordering: compiler-emitted s_waitcnt vmcnt(0)
// before s_barrier drains all waves' write-through stores to MALL, then tid0
// publishes the flag. Consumer: relaxed system-scope spin (always reads
// MALL), then cache-bypassing data loads issued after flag observation.
// Publish-then-wait double-buffer protocol identical to R5 (verified).

#define BB 2
#define HH 1024
#define WW 1024
#define NPIX (HH * WW)
#define CVN (1023 * 1024)
#define CVPN (1025 * 1024)
#define SHW (128 * 128)
#define LL 0.24f
#define KK2 (0.03f * 0.03f)
#define EPSF 1e-8f
#define DEPSF 0.1f
#define NPRE 64
#define NB 512            // persistent grid: 2 per CU on 256 CUs (co-resident)
#define TPB 256
#define FSTRIDE 16        // flags padded to one cacheline each

#define SYS_LD(p)     __hip_atomic_load((p), __ATOMIC_RELAXED, __HIP_MEMORY_SCOPE_SYSTEM)
#define SYS_ST(p, v)  __hip_atomic_store((p), (v), __ATOMIC_RELAXED, __HIP_MEMORY_SCOPE_SYSTEM)

__global__ void setup_kernel(const float* __restrict__ src, float* __restrict__ shiftOut,
                             unsigned* __restrict__ flags) {
    int tid = threadIdx.x;
    // zero neighbor-sync flags (ws is 0xAA-poisoned before every call)
    for (int i = tid; i < NB * FSTRIDE; i += TPB) flags[i] = 0u;
    float m = 1e30f;
    for (int i = tid; i < BB * SHW; i += TPB) m = fminf(m, src[i]);
    for (int off = 32; off > 0; off >>= 1) m = fminf(m, __shfl_down(m, off));
    __shared__ float sm[4];
    if ((tid & 63) == 0) sm[tid >> 6] = m;
    __syncthreads();
    if (tid == 0) {
        float mm = fminf(fminf(sm[0], sm[1]), fminf(sm[2], sm[3]));
        shiftOut[0] = (mm <= DEPSF) ? DEPSF : 0.0f;
    }
}

__global__ void init_kernel(const float* __restrict__ guide, const float* __restrict__ yb,
                            const float* __restrict__ shiftPtr, float* __restrict__ img0,
                            float* __restrict__ cv_out, float* __restrict__ ch_out,
                            float* __restrict__ cvp, float* __restrict__ chp) {
    int idx = blockIdx.x * blockDim.x + threadIdx.x;
    if (idx >= BB * NPIX) return;
    int b = idx >> 20;
    int p = idx & (NPIX - 1);
    int y = p >> 10;
    int x = p & 1023;
    const float* gb = guide + (size_t)b * 3 * NPIX;
    const float* yBb = yb + (size_t)b * NPIX;
    float c0 = yBb[p];
    img0[(size_t)b * NPIX + p] = c0 + shiftPtr[0];
    // shift cancels in finite diffs -> cv/ch from raw y_bicubic.
    float* cvpb = cvp + (size_t)b * CVPN;
    float* chpb = chp + (size_t)b * NPIX;
    if (y < HH - 1) {
        float d = fabsf(gb[p + WW] - gb[p])
                + fabsf(gb[NPIX + p + WW] - gb[NPIX + p])
                + fabsf(gb[2 * NPIX + p + WW] - gb[2 * NPIX + p])
                + fabsf(yBb[p + WW] - c0);
        d *= 0.25f;
        float v = 1.0f / (1.0f + (d * d) / KK2);
        cv_out[(size_t)b * CVN + y * WW + x] = v;
        cvpb[(y + 1) * WW + x] = v;           // padded: row r holds cv[r-1]
    } else {
        cvpb[x] = 0.f;
        cvpb[1024 * WW + x] = 0.f;
    }
    if (x < WW - 1) {
        float d = fabsf(gb[p + 1] - gb[p])
                + fabsf(gb[NPIX + p + 1] - gb[NPIX + p])
                + fabsf(gb[2 * NPIX + p + 1] - gb[2 * NPIX + p])
                + fabsf(yBb[p + 1] - c0);
        d *= 0.25f;
        float v = 1.0f / (1.0f + (d * d) / KK2);
        ch_out[(size_t)b * CVN + y * 1023 + x] = v;
        chpb[y * WW + x] = v;                 // padded stride-1024, col 1023 = 0
    } else {
        chpb[y * WW + 1023] = 0.f;
    }
}

__device__ inline void spin_ge(const unsigned* f, unsigned target) {
    // system-scope relaxed load bypasses L1+L2 -> always observes MALL state;
    // no acquire fence needed (data loads below also bypass caches and are
    // issued strictly after this returns).
    while (SYS_LD(f) < target)
        __builtin_amdgcn_s_sleep(1);
}

// LDS tile: row i <-> global row tileY*32-1+i (i=0..33), col j <-> tile col j-1
#define IMT(i, j) imt[(i) * 132 + (j)]

__launch_bounds__(TPB, 2)
__global__ void persist_kernel(const float* __restrict__ img0, float* __restrict__ out,
                               const float* __restrict__ cvp, const float* __restrict__ chp,
                               const float* __restrict__ src, const float* __restrict__ mask,
                               const float* __restrict__ shiftPtr,
                               float* __restrict__ bufRow, float* __restrict__ bufCol,
                               unsigned* __restrict__ flags) {
    __shared__ float imt[34 * 132];
    int blk = blockIdx.x;
    int b = blk >> 8;
    int r = blk & 255;
    int tileY = r >> 3;          // 0..31
    int tileX = r & 7;           // 0..7
    int tid = threadIdx.x;
    int cyL = tid >> 5;          // 0..7
    int g = tid & 31;            // 0..31
    int lx0 = g * 4;
    int ly0 = cyL * 4;
    int gx = tileX * 128 + lx0;
    int gy = tileY * 32 + ly0;   // first global row owned by this thread

    const float* im0 = img0 + (size_t)b * NPIX;
    const float* cvpb = cvp + (size_t)b * CVPN;
    const float* chpb = chp + (size_t)b * NPIX;
    float shift = shiftPtr[0];

    // conductances resident in registers for all 64 steps
    float4 cvR[5], chR[4];
    float hmR[4];
#pragma unroll
    for (int j = 0; j < 5; ++j)
        cvR[j] = *(const float4*)(cvpb + (size_t)(gy + j) * WW + gx);
#pragma unroll
    for (int k = 0; k < 4; ++k) {
        chR[k] = *(const float4*)(chpb + (size_t)(gy + k) * WW + gx);
        hmR[k] = (gx > 0) ? chpb[(size_t)(gy + k) * WW + gx - 1] : 0.f;
    }
    int sy = tileY * 4 + (cyL >> 1);
    int sx = tileX * 16 + (g >> 1);
    int sidx = b * SHW + sy * 128 + sx;
    float sval = src[sidx] + shift;
    bool masked = mask[sidx] < 0.5f;

    // initial LDS fill (interior + halos from init image; 0 past image edges,
    // where the matching conductance is 0 so the value is never used)
#pragma unroll
    for (int k = 0; k < 4; ++k)
        *(float4*)&IMT(1 + ly0 + k, 1 + lx0) = *(const float4*)(im0 + (size_t)(gy + k) * WW + gx);
    float4 z4 = make_float4(0.f, 0.f, 0.f, 0.f);
    if (cyL == 0)
        *(float4*)&IMT(0, 1 + lx0) =
            (tileY > 0) ? *(const float4*)(im0 + (size_t)(gy - 1) * WW + gx) : z4;
    if (cyL == 7)
        *(float4*)&IMT(33, 1 + lx0) =
            (tileY < 31) ? *(const float4*)(im0 + (size_t)(gy + 4) * WW + gx) : z4;
    if (g == 0) {
#pragma unroll
        for (int k = 0; k < 4; ++k)
            IMT(1 + ly0 + k, 0) = (tileX > 0) ? im0[(size_t)(gy + k) * WW + gx - 1] : 0.f;
    }
    if (g == 31) {
#pragma unroll
        for (int k = 0; k < 4; ++k)
            IMT(1 + ly0 + k, 129) = (tileX < 7) ? im0[(size_t)(gy + k) * WW + gx + 4] : 0.f;
    }
    __syncthreads();

    float4 nv[4];
    for (int t = 0; t < NPRE; ++t) {
        if (t > 0) {
            int buf = (t - 1) & 1;
            // each stager spins on the flag guarding the data it stages;
            // halo reads are cache-bypassing (MALL-coherent) word loads
            if (cyL == 0 && tileY > 0) {
                spin_ge(&flags[(blk - 8) * FSTRIDE], (unsigned)t);
                const float* p = &bufRow[(((size_t)buf * NB + blk - 8) * 2 + 1) * 128 + lx0];
                IMT(0, 1 + lx0 + 0) = SYS_LD(p + 0);
                IMT(0, 1 + lx0 + 1) = SYS_LD(p + 1);
                IMT(0, 1 + lx0 + 2) = SYS_LD(p + 2);
                IMT(0, 1 + lx0 + 3) = SYS_LD(p + 3);
            }
            if (cyL == 7 && tileY < 31) {
                spin_ge(&flags[(blk + 8) * FSTRIDE], (unsigned)t);
                const float* p = &bufRow[(((size_t)buf * NB + blk + 8) * 2 + 0) * 128 + lx0];
                IMT(33, 1 + lx0 + 0) = SYS_LD(p + 0);
                IMT(33, 1 + lx0 + 1) = SYS_LD(p + 1);
                IMT(33, 1 + lx0 + 2) = SYS_LD(p + 2);
                IMT(33, 1 + lx0 + 3) = SYS_LD(p + 3);
            }
            if (g == 0 && tileX > 0) {
                spin_ge(&flags[(blk - 1) * FSTRIDE], (unsigned)t);
                const float* p = &bufCol[(((size_t)buf * NB + blk - 1) * 2 + 1) * 32 + ly0];
#pragma unroll
                for (int k = 0; k < 4; ++k)
                    IMT(1 + ly0 + k, 0) = SYS_LD(p + k);
            }
            if (g == 31 && tileX < 7) {
                spin_ge(&flags[(blk + 1) * FSTRIDE], (unsigned)t);
                const float* p = &bufCol[(((size_t)buf * NB + blk + 1) * 2 + 0) * 32 + ly0];
#pragma unroll
                for (int k = 0; k < 4; ++k)
                    IMT(1 + ly0 + k, 129) = SYS_LD(p + k);
            }
            __syncthreads();   // halos staged before anyone computes
        }

        // diffuse + adjust from LDS state_t -> nv = state_{t+1}
        float4 rUp = *(float4*)&IMT(ly0, 1 + lx0);
        float4 rC  = *(float4*)&IMT(ly0 + 1, 1 + lx0);
        float csum = 0.f;
#pragma unroll
        for (int k = 0; k < 4; ++k) {
            float4 rDn = *(float4*)&IMT(ly0 + 2 + k, 1 + lx0);
            float4 cu = cvR[k], cd = cvR[k + 1], h4 = chR[k];
            float xl = __shfl_up(rC.w, 1);
            float xr = __shfl_down(rC.x, 1);
            float hm = hmR[k];
            if (g == 0)  xl = IMT(1 + ly0 + k, 0);
            if (g == 31) xr = IMT(1 + ly0 + k, 129);
            float4 acc;
            acc.x = rC.x + LL * (cd.x * (rDn.x - rC.x) - cu.x * (rC.x - rUp.x)
                               + h4.x * (rC.y - rC.x) - hm   * (rC.x - xl));
            acc.y = rC.y + LL * (cd.y * (rDn.y - rC.y) - cu.y * (rC.y - rUp.y)
                               + h4.y * (rC.z - rC.y) - h4.x * (rC.y - rC.x));
            acc.z = rC.z + LL * (cd.z * (rDn.z - rC.z) - cu.z * (rC.z - rUp.z)
                               + h4.z * (rC.w - rC.z) - h4.y * (rC.z - rC.y));
            acc.w = rC.w + LL * (cd.w * (rDn.w - rC.w) - cu.w * (rC.w - rUp.w)
                               + h4.w * (xr   - rC.w) - h4.z * (rC.w - rC.z));
            nv[k] = acc;
            csum += acc.x + acc.y + acc.z + acc.w;
            rUp = rC; rC = rDn;
        }
        csum += __shfl_xor(csum, 1);
        csum += __shfl_xor(csum, 32);
        float ratio = masked ? 1.0f : sval / (csum * (1.0f / 64.0f) + EPSF);
#pragma unroll
        for (int k = 0; k < 4; ++k) {
            nv[k].x *= ratio; nv[k].y *= ratio; nv[k].z *= ratio; nv[k].w *= ratio;
        }

        if (t < NPRE - 1) {
            __syncthreads();   // all reads of state_t done
#pragma unroll
            for (int k = 0; k < 4; ++k)
                *(float4*)&IMT(1 + ly0 + k, 1 + lx0) = nv[k];
            int buf = t & 1;
            // edge publishes: write-through (sc0 sc1) word stores to MALL
            if (cyL == 0) {
                float* p = &bufRow[(((size_t)buf * NB + blk) * 2 + 0) * 128 + lx0];
                SYS_ST(p + 0, nv[0].x); SYS_ST(p + 1, nv[0].y);
                SYS_ST(p + 2, nv[0].z); SYS_ST(p + 3, nv[0].w);
            }
            if (cyL == 7) {
                float* p = &bufRow[(((size_t)buf * NB + blk) * 2 + 1) * 128 + lx0];
                SYS_ST(p + 0, nv[3].x); SYS_ST(p + 1, nv[3].y);
                SYS_ST(p + 2, nv[3].z); SYS_ST(p + 3, nv[3].w);
            }
            if (g == 0) {
                float* p = &bufCol[(((size_t)buf * NB + blk) * 2 + 0) * 32 + ly0];
#pragma unroll
                for (int k = 0; k < 4; ++k) SYS_ST(p + k, nv[k].x);
            }
            if (g == 31) {
                float* p = &bufCol[(((size_t)buf * NB + blk) * 2 + 1) * 32 + ly0];
#pragma unroll
                for (int k = 0; k < 4; ++k) SYS_ST(p + k, nv[k].w);
            }
            // s_barrier: compiler drains each wave's vmcnt to 0 first, so all
            // write-through edge stores are MALL-committed when this returns.
            __syncthreads();
            if (tid == 0) {
                __builtin_amdgcn_s_waitcnt(0);   // belt-and-braces (own wave)
                SYS_ST(&flags[blk * FSTRIDE], (unsigned)(t + 1));
            }
        }
    }

    // final output: state_64 - shift, straight from registers
    float* ob = out + (size_t)b * NPIX;
#pragma unroll
    for (int k = 0; k < 4; ++k) {
        float4 v = nv[k];
        v.x -= shift; v.y -= shift; v.z -= shift; v.w -= shift;
        *(float4*)(ob + (size_t)(gy + k) * WW + gx) = v;
    }
}

extern "C" void kernel_launch(void* const* d_in, const int* in_sizes, int n_in,
                              void* d_out, int out_size, void* d_ws, size_t ws_size,
                              hipStream_t stream) {
    const float* guide = (const float*)d_in[0];   // [2,3,1024,1024]
    const float* yb    = (const float*)d_in[1];   // [2,1,1024,1024]
    const float* src   = (const float*)d_in[2];   // [2,1,128,128]
    const float* mask  = (const float*)d_in[3];   // [2,1,128,128]

    float* out    = (float*)d_out;                       // y_pred [2,1,1024,1024]
    float* out_cv = out + (size_t)BB * NPIX;
    float* out_ch = out_cv + (size_t)BB * CVN;

    float* wsf = (float*)d_ws;
    float* shift = wsf;                                  // [256] slot
    unsigned* flags = (unsigned*)(wsf + 256);            // 512*16 uints
    float* imgA = wsf + 256 + NB * FSTRIDE;              // init image, 2*NPIX
    float* cvp  = imgA + (size_t)BB * NPIX;              // 2*1025*1024
    float* chp  = cvp + (size_t)BB * CVPN;               // 2*1024*1024
    float* bufRow = chp + (size_t)BB * NPIX;             // 2*512*2*128
    float* bufCol = bufRow + (size_t)2 * NB * 2 * 128;   // 2*512*2*32

    setup_kernel<<<1, TPB, 0, stream>>>(src, shift, flags);
    init_kernel<<<(BB * NPIX) / TPB, TPB, 0, stream>>>(guide, yb, shift, imgA,
                                                       out_cv, out_ch, cvp, chp);

    persist_kernel<<<NB, TPB, 0, stream>>>(imgA, out, cvp, chp, src, mask, shift,
                                           bufRow, bufCol, flags);
}